// Round 3
// baseline (157.219 us; speedup 1.0000x reference)
//
#include <hip/hip_runtime.h>
#include <math.h>

#define N 4096
#define IN_F 256
#define OUT_F 64
#define HEADS 4
#define NEG 0.2f
#define JSL 1024                 // j-slice per wave (2 heads x 4 slices = 8 waves)
#define NC2 (JSL / 32)           // 32 chunks per wave
#define LOG2E 1.44269504088896f
#define RSTR 68                  // reduce-buffer row stride (floats): 64 O + 1 l + pad

typedef float f32x4 __attribute__((ext_vector_type(4)));
typedef float f32x2 __attribute__((ext_vector_type(2)));
typedef short short8 __attribute__((ext_vector_type(8)));

#define FMA4S(A, s, V) do { (A).x = fmaf((s),(V).x,(A).x); (A).y = fmaf((s),(V).y,(A).y); \
                            (A).z = fmaf((s),(V).z,(A).z); (A).w = fmaf((s),(V).w,(A).w); } while(0)

// zero P unless bit R of MS is set: AND float bits with v_bfe_i32 sign-extended bit
#define MSEL(P, MS, R) (P) = __uint_as_float(__float_as_uint(P) & \
                         (unsigned)__builtin_amdgcn_sbfe((int)(MS), (R), 1))

__device__ __forceinline__ unsigned short f2bf(float x) {
  unsigned int u = __float_as_uint(x);
  u += 0x7fffu + ((u >> 16) & 1u);   // RNE
  return (unsigned short)(u >> 16);
}

__device__ __forceinline__ float exp2_fast(float x) {
#if __has_builtin(__builtin_amdgcn_exp2f)
  return __builtin_amdgcn_exp2f(x);
#else
  return exp2f(x);
#endif
}

// pack bf16(p1)<<16 | bf16(p0), round-half-up (v_perm; m240: do NOT use
// inline-asm v_cvt_pk_bf16_f32 here — it blocked scheduling, R2 regression)
__device__ __forceinline__ int pack_bf2(float p0, float p1) {
  unsigned u0 = __float_as_uint(p0) + 0x8000u;
  unsigned u1 = __float_as_uint(p1) + 0x8000u;
  return (int)__builtin_amdgcn_perm(u1, u0, 0x07060302u);
}

// ---------------------------------------------------------------------------
// Kernel 1: prep GEMM only. xt = x @ W[h] (32-row tile, LDS-staged) ->
// src/dst (log2e-scaled) + xtB (bf16 B-frag). The adj->bitmask stream moved
// into k_flash (R3): it was 10.6 us of pure HBM that serialized against
// k_flash's VALU phase; merged they overlap.
// ---------------------------------------------------------------------------
__global__ __launch_bounds__(256) void k_prep(const float* __restrict__ x,
                                              const float* __restrict__ W,
                                              const float* __restrict__ a,
                                              short* __restrict__ xtB,
                                              float* __restrict__ src,
                                              float* __restrict__ dst) {
  __shared__ __align__(16) float xls[32 * 68];
  __shared__ __align__(16) float wls[64 * 64];
  const int t = threadIdx.x;

  const int h  = blockIdx.x >> 7;
  const int bx = blockIdx.x & 127;
  const int i0 = bx * 32;
  const int fg = t & 15;
  const int rg = t >> 4;

  float4 acc[2];
  acc[0] = acc[1] = make_float4(0.f, 0.f, 0.f, 0.f);

  const float4* xg = (const float4*)x;
  const float4* wg = (const float4*)W;
  float4* xls4 = (float4*)xls;
  float4* wls4 = (float4*)wls;
  const float4* xr4 = (const float4*)xls;
  const float4* wr4 = (const float4*)wls;

  for (int kt = 0; kt < 4; ++kt) {
    __syncthreads();
    #pragma unroll
    for (int s = 0; s < 2; ++s) {
      int f4i = t + 256 * s;
      int row = f4i >> 4, c4 = f4i & 15;
      xls4[row * 17 + c4] = xg[(size_t)(i0 + row) * 64 + kt * 16 + c4];
    }
    #pragma unroll
    for (int s = 0; s < 4; ++s) {
      int f4i = t + 256 * s;
      int kk = f4i >> 4, c4 = f4i & 15;
      wls4[kk * 16 + c4] = wg[(size_t)(h * 256 + kt * 64 + kk) * 16 + c4];
    }
    __syncthreads();
    #pragma unroll 4
    for (int kk = 0; kk < 64; kk += 4) {
      float4 wv0 = wr4[(kk + 0) * 16 + fg];
      float4 wv1 = wr4[(kk + 1) * 16 + fg];
      float4 wv2 = wr4[(kk + 2) * 16 + fg];
      float4 wv3 = wr4[(kk + 3) * 16 + fg];
      #pragma unroll
      for (int q = 0; q < 2; ++q) {
        float4 xv = xr4[(rg * 2 + q) * 17 + (kk >> 2)];
        FMA4S(acc[q], xv.x, wv0);
        FMA4S(acc[q], xv.y, wv1);
        FMA4S(acc[q], xv.z, wv2);
        FMA4S(acc[q], xv.w, wv3);
      }
    }
  }

  const float4* a4 = (const float4*)a;
  float4 as = a4[h * 32 + fg];
  float4 ad = a4[h * 32 + 16 + fg];
  as.x *= LOG2E; as.y *= LOG2E; as.z *= LOG2E; as.w *= LOG2E;
  ad.x *= LOG2E; ad.y *= LOG2E; ad.z *= LOG2E; ad.w *= LOG2E;
  #pragma unroll
  for (int q = 0; q < 2; ++q) {
    float s_ = acc[q].x * as.x + acc[q].y * as.y + acc[q].z * as.z + acc[q].w * as.w;
    float d_ = acc[q].x * ad.x + acc[q].y * ad.y + acc[q].z * ad.z + acc[q].w * ad.w;
    #pragma unroll
    for (int off = 1; off < 16; off <<= 1) {
      s_ += __shfl_xor(s_, off, 64);
      d_ += __shfl_xor(d_, off, 64);
    }
    if (fg == 0) {
      int r = rg * 2 + q;
      src[h * N + i0 + r] = s_;
      dst[h * N + i0 + r] = d_;
    }
  }

  __syncthreads();
  #pragma unroll
  for (int q = 0; q < 2; ++q) {
    *(float4*)&xls[(rg * 2 + q) * 68 + fg * 4] = acc[q];
  }
  __syncthreads();

  {
    const int lane = t & 63;
    const int g    = t >> 6;
    const int q    = lane >> 4;
    const int m    = lane & 15;
    short8 bv;
    #pragma unroll
    for (int r = 0; r < 8; ++r) {
      bv[r] = (short)f2bf(xls[(q * 8 + r) * 68 + g * 16 + m]);
    }
    ((short8*)xtB)[((size_t)(h * 128 + bx) * 4 + g) * 64 + lane] = bv;
  }
}

// ---------------------------------------------------------------------------
// Kernel 2: fused adj-stream + flash PV + in-block reduction.
// grid (128, 2): block = 32 i-rows x 2 heads, 512 thr = 8 waves
// (wave = head-half x j-slice of 1024, 32 chunks). Each wave converts its own
// adj chunk (rows x 32 j) to mask bits in-loop: 4 coalesced int4 loads
// (2-chunk-deep prefetch), bit-pack nibbles -> 256B/wave LDS scratch ->
// 2x ds_read_b64 + nibble-compress -> cM0/cM1. The 67 MB adj HBM stream now
// overlaps the logit VALU instead of serializing in a separate kernel.
// Blocks bx and bx+128 (same rows, other head pair) land on the same XCD
// (idx%8) concurrently -> 2nd read is an L2 hit.
// NOTE: bit-pack relies on adj values being exactly {0,1} (randint(0,2)).
// ---------------------------------------------------------------------------
__global__ __launch_bounds__(512, 2) void k_flash(const int* __restrict__ adj,
                                                  const float* __restrict__ src,
                                                  const float* __restrict__ dst,
                                                  const short* __restrict__ xtB,
                                                  float* __restrict__ out) {
  // 8704 floats = 34816 B. During j-loop: [0,8192) = dst cache (2 heads),
  // [8192,8704) = nibble scratch (8 waves x 256 B, exactly fits).
  // After loop: 4 reduce slots of 32 x RSTR.
  __shared__ __align__(16) float smem[4 * 32 * RSTR];
  const int t    = threadIdx.x;
  const int lane = t & 63;
  const int w    = t >> 6;
  const int hb   = blockIdx.y;          // head pair
  const int i0   = blockIdx.x * 32;
  const int hh   = w >> 2;              // head within pair
  const int sl   = w & 3;               // j-slice
  const int h    = hb * 2 + hh;
  const int jbase = sl * JSL;
  const int q    = lane >> 4;
  const int m    = lane & 15;
  const int koff = q * 8;

  // stage dst rows for both heads: smem[hh*4096 + j]
  {
    const float4* dgA = (const float4*)(dst + (size_t)(hb * 2) * N);
    const float4* dgB = (const float4*)(dst + (size_t)(hb * 2 + 1) * N);
    float4* ds4 = (float4*)smem;
    ds4[t]        = dgA[t];
    ds4[t + 512]  = dgA[t + 512];
    ds4[t + 1024] = dgB[t];
    ds4[t + 1536] = dgB[t + 512];
  }

  float sv = (lane < 32) ? src[h * N + i0 + lane] : 0.f;
  const float s0 = __shfl(sv, m, 64);
  const float s1 = __shfl(sv, 16 + m, 64);
  __syncthreads();

  f32x4 acc0[4], acc1[4], accL0, accL1;
  #pragma unroll
  for (int g = 0; g < 4; ++g) { acc0[g] = (f32x4)(0.f); acc1[g] = (f32x4)(0.f); }
  accL0 = (f32x4)(0.f);
  accL1 = (f32x4)(0.f);

  short8 ones;
  #pragma unroll
  for (int r = 0; r < 8; ++r) ones[r] = (short)0x3F80;

  const f32x2 s02 = (f32x2)(s0);
  const f32x2 s12 = (f32x2)(s1);

  // nibble scratch: wave-private 32 rows x 8 bytes
  char* nib = (char*)smem + 32768 + w * 256;
  const int nboff = (lane >> 3) * 8 + (lane & 7);  // +L*64 per load group
  const char* nibr = nib + m * 8;                  // read: row m (+128 for m+16)

  // adj int4 base: row i0+(lane>>3), col jbase + (lane&7)*4; +8192 per 8-row group
  const int4* apb = (const int4*)adj;
  const size_t a0 = (size_t)(i0 + (lane >> 3)) * 1024 + (size_t)(jbase >> 2) + (lane & 7);

  const short8* xbb = (const short8*)xtB + ((size_t)(h * 128 + (jbase >> 5)) * 4) * 64 + lane;

#define LOADC(AJ, DB, CIDX) do {                                           \
    AJ[0] = apb[a0 +         (size_t)(CIDX) * 8];                          \
    AJ[1] = apb[a0 +  8192 + (size_t)(CIDX) * 8];                          \
    AJ[2] = apb[a0 + 16384 + (size_t)(CIDX) * 8];                          \
    AJ[3] = apb[a0 + 24576 + (size_t)(CIDX) * 8];                          \
    const short8* bb_ = xbb + (size_t)(CIDX) * 256;                        \
    DB[0] = bb_[0]; DB[1] = bb_[64]; DB[2] = bb_[128]; DB[3] = bb_[192];   \
  } while (0)

#define NIBCOMP(R64, MW) do {                                              \
    unsigned lo_ = (unsigned)(R64), hi_ = (unsigned)((R64) >> 32);         \
    lo_ = (lo_ | (lo_ >> 4)) & 0x00ff00ffu;                                \
    lo_ = (lo_ | (lo_ >> 8)) & 0x0000ffffu;                                \
    hi_ = (hi_ | (hi_ >> 4)) & 0x00ff00ffu;                                \
    hi_ = (hi_ | (hi_ >> 8)) & 0x0000ffffu;                                \
    MW  = lo_ | (hi_ << 16);                                               \
  } while (0)

#define COMPUTE(AJ, DB, C) do {                                            \
    nib[  0 + nboff] = (char)(AJ[0].x | (AJ[0].y << 1) | (AJ[0].z << 2) | (AJ[0].w << 3)); \
    nib[ 64 + nboff] = (char)(AJ[1].x | (AJ[1].y << 1) | (AJ[1].z << 2) | (AJ[1].w << 3)); \
    nib[128 + nboff] = (char)(AJ[2].x | (AJ[2].y << 1) | (AJ[2].z << 2) | (AJ[2].w << 3)); \
    nib[192 + nboff] = (char)(AJ[3].x | (AJ[3].y << 1) | (AJ[3].z << 2) | (AJ[3].w << 3)); \
    unsigned long long r0_ = *(const unsigned long long*)(nibr);           \
    unsigned long long r1_ = *(const unsigned long long*)(nibr + 128);     \
    unsigned cM0, cM1;                                                     \
    NIBCOMP(r0_, cM0);                                                     \
    NIBCOMP(r1_, cM1);                                                     \
    const float* dp_ = &smem[hh * 4096 + jbase + (C) * 32 + koff];         \
    union { float4 v[2]; f32x2 h2[4]; float f[8]; } du;                    \
    du.v[0] = *(const float4*)dp_;                                         \
    du.v[1] = *(const float4*)(dp_ + 4);                                   \
    unsigned ms0 = cM0 >> koff;                                            \
    unsigned ms1 = cM1 >> koff;                                            \
    int av0[4], av1[4];                                                    \
    _Pragma("unroll")                                                      \
    for (int r2 = 0; r2 < 4; ++r2) {                                       \
      f32x2 d2 = du.h2[r2];                                                \
      f32x2 e0 = s02 + d2;                                                 \
      f32x2 el0 = __builtin_elementwise_max(e0, e0 * NEG);                 \
      f32x2 e1 = s12 + d2;                                                 \
      f32x2 el1 = __builtin_elementwise_max(e1, e1 * NEG);                 \
      float p0a = exp2_fast(el0.x), p0b = exp2_fast(el0.y);                \
      float p1a = exp2_fast(el1.x), p1b = exp2_fast(el1.y);                \
      MSEL(p0a, ms0, 2 * r2);  MSEL(p0b, ms0, 2 * r2 + 1);                 \
      MSEL(p1a, ms1, 2 * r2);  MSEL(p1b, ms1, 2 * r2 + 1);                 \
      av0[r2] = pack_bf2(p0a, p0b);                                        \
      av1[r2] = pack_bf2(p1a, p1b);                                        \
    }                                                                      \
    short8 af0 = __builtin_bit_cast(short8, *(int4*)av0);                  \
    short8 af1 = __builtin_bit_cast(short8, *(int4*)av1);                  \
    acc0[0] = __builtin_amdgcn_mfma_f32_16x16x32_bf16(af0, DB[0], acc0[0], 0, 0, 0); \
    acc0[1] = __builtin_amdgcn_mfma_f32_16x16x32_bf16(af0, DB[1], acc0[1], 0, 0, 0); \
    acc0[2] = __builtin_amdgcn_mfma_f32_16x16x32_bf16(af0, DB[2], acc0[2], 0, 0, 0); \
    acc0[3] = __builtin_amdgcn_mfma_f32_16x16x32_bf16(af0, DB[3], acc0[3], 0, 0, 0); \
    accL0   = __builtin_amdgcn_mfma_f32_16x16x32_bf16(af0, ones,  accL0,   0, 0, 0); \
    acc1[0] = __builtin_amdgcn_mfma_f32_16x16x32_bf16(af1, DB[0], acc1[0], 0, 0, 0); \
    acc1[1] = __builtin_amdgcn_mfma_f32_16x16x32_bf16(af1, DB[1], acc1[1], 0, 0, 0); \
    acc1[2] = __builtin_amdgcn_mfma_f32_16x16x32_bf16(af1, DB[2], acc1[2], 0, 0, 0); \
    acc1[3] = __builtin_amdgcn_mfma_f32_16x16x32_bf16(af1, DB[3], acc1[3], 0, 0, 0); \
    accL1   = __builtin_amdgcn_mfma_f32_16x16x32_bf16(af1, ones,  accL1,   0, 0, 0); \
  } while (0)

  // 2-chunk-deep prefetch (2 waves/SIMD -> depth 1 can't cover HBM latency)
  int4 AJ0[4], AJ1[4];
  short8 B0[4], B1[4];
  LOADC(AJ0, B0, 0);
  LOADC(AJ1, B1, 1);

  for (int c = 0; c < NC2; c += 2) {
    COMPUTE(AJ0, B0, c);
    { const int cn = (c + 2 < NC2) ? c + 2 : c; LOADC(AJ0, B0, cn); }
    COMPUTE(AJ1, B1, c + 1);
    { const int cn = (c + 3 < NC2) ? c + 3 : c + 1; LOADC(AJ1, B1, cn); }
  }
#undef LOADC
#undef NIBCOMP
#undef COMPUTE

  // ---- in-block reduction: 4 j-slice partials per head (fp32) -----------
  // slots: head hh uses slots {hh*2, hh*2+1}
#define RED_ST(SLOT) do {                                                  \
    float* part_ = smem + (SLOT) * (32 * RSTR);                            \
    _Pragma("unroll")                                                      \
    for (int g = 0; g < 4; ++g)                                            \
      _Pragma("unroll")                                                    \
      for (int rr = 0; rr < 4; ++rr) {                                     \
        part_[(q * 4 + rr) * RSTR + g * 16 + m]      = acc0[g][rr];        \
        part_[(q * 4 + rr + 16) * RSTR + g * 16 + m] = acc1[g][rr];        \
      }                                                                    \
    if (m == 0) {                                                          \
      _Pragma("unroll")                                                    \
      for (int rr = 0; rr < 4; ++rr) {                                     \
        part_[(q * 4 + rr) * RSTR + 64]      = accL0[rr];                  \
        part_[(q * 4 + rr + 16) * RSTR + 64] = accL1[rr];                  \
      }                                                                    \
    }                                                                      \
  } while (0)
#define RED_ADD(SLOT) do {                                                 \
    const float* part_ = smem + (SLOT) * (32 * RSTR);                      \
    _Pragma("unroll")                                                      \
    for (int g = 0; g < 4; ++g)                                            \
      _Pragma("unroll")                                                    \
      for (int rr = 0; rr < 4; ++rr) {                                     \
        acc0[g][rr] += part_[(q * 4 + rr) * RSTR + g * 16 + m];            \
        acc1[g][rr] += part_[(q * 4 + rr + 16) * RSTR + g * 16 + m];       \
      }                                                                    \
    _Pragma("unroll")                                                      \
    for (int rr = 0; rr < 4; ++rr) {                                       \
      accL0[rr] += part_[(q * 4 + rr) * RSTR + 64];                        \
      accL1[rr] += part_[(q * 4 + rr + 16) * RSTR + 64];                   \
    }                                                                      \
  } while (0)

  __syncthreads();                       // j-loop done; dst cache/nib dead
  if (sl >= 2) RED_ST(hh * 2 + (sl - 2));      // slices 2,3 -> slots
  __syncthreads();
  if (sl < 2) { RED_ADD(hh * 2 + sl); RED_ST(hh * 2 + sl); }  // pairwise sums
  __syncthreads();
#undef RED_ST
#undef RED_ADD

  // ---- final 2-slot sum + normalize + coalesced store -------------------
  {
    const int hf  = t >> 8;              // head within pair
    const int row = (t >> 3) & 31;
    const int c8  = t & 7;               // 8 floats per thread
    const float* pA = smem + (hf * 2)     * (32 * RSTR) + row * RSTR;
    const float* pB = smem + (hf * 2 + 1) * (32 * RSTR) + row * RSTR;
    const float il = 1.f / (pA[64] + pB[64]);
    float4 v0 = *(const float4*)(pA + c8 * 8);
    float4 u0 = *(const float4*)(pB + c8 * 8);
    float4 v1 = *(const float4*)(pA + c8 * 8 + 4);
    float4 u1 = *(const float4*)(pB + c8 * 8 + 4);
    v0.x = (v0.x + u0.x) * il; v0.y = (v0.y + u0.y) * il;
    v0.z = (v0.z + u0.z) * il; v0.w = (v0.w + u0.w) * il;
    v1.x = (v1.x + u1.x) * il; v1.y = (v1.y + u1.y) * il;
    v1.z = (v1.z + u1.z) * il; v1.w = (v1.w + u1.w) * il;
    float4* og = (float4*)out + (size_t)(i0 + row) * 64 + (hb * 2 + hf) * 16 + c8 * 2;
    og[0] = v0;
    og[1] = v1;
  }
}

extern "C" void kernel_launch(void* const* d_in, const int* in_sizes, int n_in,
                              void* d_out, int out_size, void* d_ws, size_t ws_size,
                              hipStream_t stream) {
  const float* x   = (const float*)d_in[0];
  const float* W   = (const float*)d_in[1];
  const float* a   = (const float*)d_in[2];
  const int*   adj = (const int*)d_in[3];
  float* out = (float*)d_out;

  float* ws    = (float*)d_ws;
  short* xtB   = (short*)ws;                                // H*N*64 bf16 = 2 MB
  float* src   = ws + 524288;                               // H*N
  float* dst   = src + HEADS * N;                           // H*N

  k_prep<<<dim3(512), 256, 0, stream>>>(x, W, a, xtB, src, dst);
  k_flash<<<dim3(N / 32, 2), 512, 0, stream>>>(adj, src, dst, xtB, out);
}

// Round 4
// 133.287 us; speedup vs baseline: 1.1796x; 1.1796x over previous
//
#include <hip/hip_runtime.h>
#include <math.h>

#define N 4096
#define IN_F 256
#define OUT_F 64
#define HEADS 4
#define NEG 0.2f
#define JLEN 512                 // j-slice per wave
#define NC (JLEN / 32)           // 16 chunks per wave
#define LOG2E 1.44269504088896f
#define RSTR 68                  // reduce-buffer row stride (floats): 64 O + 1 l + pad

typedef float f32x4 __attribute__((ext_vector_type(4)));
typedef float f32x2 __attribute__((ext_vector_type(2)));
typedef short short8 __attribute__((ext_vector_type(8)));

#define FMA4S(A, s, V) do { (A).x = fmaf((s),(V).x,(A).x); (A).y = fmaf((s),(V).y,(A).y); \
                            (A).z = fmaf((s),(V).z,(A).z); (A).w = fmaf((s),(V).w,(A).w); } while(0)

// zero P unless bit R of MS is set: AND float bits with v_bfe_i32 sign-extended bit
#define MSEL(P, MS, R) (P) = __uint_as_float(__float_as_uint(P) & \
                         (unsigned)__builtin_amdgcn_sbfe((int)(MS), (R), 1))

__device__ __forceinline__ unsigned short f2bf(float x) {
  unsigned int u = __float_as_uint(x);
  u += 0x7fffu + ((u >> 16) & 1u);   // RNE
  return (unsigned short)(u >> 16);
}

__device__ __forceinline__ float exp2_fast(float x) {
#if __has_builtin(__builtin_amdgcn_exp2f)
  return __builtin_amdgcn_exp2f(x);
#else
  return exp2f(x);
#endif
}

// pack bf16(p1)<<16 | bf16(p0), round-half-up (v_perm; m240 + R2 regression:
// do NOT replace with inline-asm v_cvt_pk_bf16_f32 — it blocks scheduling)
__device__ __forceinline__ int pack_bf2(float p0, float p1) {
  unsigned u0 = __float_as_uint(p0) + 0x8000u;
  unsigned u1 = __float_as_uint(p1) + 0x8000u;
  return (int)__builtin_amdgcn_perm(u1, u0, 0x07060302u);
}

// ---------------------------------------------------------------------------
// Kernel 1: fused prep. Blocks [0,512): xt = x @ W[h] (32-row tile, LDS-staged)
// -> src/dst (log2e-scaled) + xtB (bf16 B-frag). Blocks [512,8704): adj ->
// bitmask stream. Data-independent partitions overlap HBM stream with GEMM.
// NOTE (R3 lesson): do NOT fold the adj stream into k_flash — a 256-block
// compute-structured kernel has too little memory-level parallelism to
// stream 67 MB (measured: 1 TB/s = 13% peak, k_flash 7.5->61 us). The
// 8192-block streamer here runs at ~80% peak. Kernel boundary stays.
// NOTE (R12 lesson): no device fences — cross-XCD L2 storm (172 vs 28 us).
// ---------------------------------------------------------------------------
__global__ __launch_bounds__(256) void k_prep(const float* __restrict__ x,
                                              const float* __restrict__ W,
                                              const float* __restrict__ a,
                                              const int* __restrict__ adj,
                                              short* __restrict__ xtB,
                                              float* __restrict__ src,
                                              float* __restrict__ dst,
                                              unsigned char* __restrict__ mbB) {
  __shared__ __align__(16) float xls[32 * 68];
  __shared__ __align__(16) float wls[64 * 64];
  const int t = threadIdx.x;

  if (blockIdx.x >= 512) {
    int tid = (blockIdx.x - 512) * 256 + t;
    const int4* a4 = (const int4*)adj + (size_t)tid * 2;
    int4 v0 = a4[0];
    int4 v1 = a4[1];
    unsigned b = 0;
    b |= (v0.x > 0) ? 0x01u : 0u;
    b |= (v0.y > 0) ? 0x02u : 0u;
    b |= (v0.z > 0) ? 0x04u : 0u;
    b |= (v0.w > 0) ? 0x08u : 0u;
    b |= (v1.x > 0) ? 0x10u : 0u;
    b |= (v1.y > 0) ? 0x20u : 0u;
    b |= (v1.z > 0) ? 0x40u : 0u;
    b |= (v1.w > 0) ? 0x80u : 0u;
    mbB[tid] = (unsigned char)b;
    return;
  }

  const int h  = blockIdx.x >> 7;
  const int bx = blockIdx.x & 127;
  const int i0 = bx * 32;
  const int fg = t & 15;
  const int rg = t >> 4;

  float4 acc[2];
  acc[0] = acc[1] = make_float4(0.f, 0.f, 0.f, 0.f);

  const float4* xg = (const float4*)x;
  const float4* wg = (const float4*)W;
  float4* xls4 = (float4*)xls;
  float4* wls4 = (float4*)wls;
  const float4* xr4 = (const float4*)xls;
  const float4* wr4 = (const float4*)wls;

  for (int kt = 0; kt < 4; ++kt) {
    __syncthreads();
    #pragma unroll
    for (int s = 0; s < 2; ++s) {
      int f4i = t + 256 * s;
      int row = f4i >> 4, c4 = f4i & 15;
      xls4[row * 17 + c4] = xg[(size_t)(i0 + row) * 64 + kt * 16 + c4];
    }
    #pragma unroll
    for (int s = 0; s < 4; ++s) {
      int f4i = t + 256 * s;
      int kk = f4i >> 4, c4 = f4i & 15;
      wls4[kk * 16 + c4] = wg[(size_t)(h * 256 + kt * 64 + kk) * 16 + c4];
    }
    __syncthreads();
    #pragma unroll 4
    for (int kk = 0; kk < 64; kk += 4) {
      float4 wv0 = wr4[(kk + 0) * 16 + fg];
      float4 wv1 = wr4[(kk + 1) * 16 + fg];
      float4 wv2 = wr4[(kk + 2) * 16 + fg];
      float4 wv3 = wr4[(kk + 3) * 16 + fg];
      #pragma unroll
      for (int q = 0; q < 2; ++q) {
        float4 xv = xr4[(rg * 2 + q) * 17 + (kk >> 2)];
        FMA4S(acc[q], xv.x, wv0);
        FMA4S(acc[q], xv.y, wv1);
        FMA4S(acc[q], xv.z, wv2);
        FMA4S(acc[q], xv.w, wv3);
      }
    }
  }

  const float4* a4 = (const float4*)a;
  float4 as = a4[h * 32 + fg];
  float4 ad = a4[h * 32 + 16 + fg];
  as.x *= LOG2E; as.y *= LOG2E; as.z *= LOG2E; as.w *= LOG2E;
  ad.x *= LOG2E; ad.y *= LOG2E; ad.z *= LOG2E; ad.w *= LOG2E;
  #pragma unroll
  for (int q = 0; q < 2; ++q) {
    float s_ = acc[q].x * as.x + acc[q].y * as.y + acc[q].z * as.z + acc[q].w * as.w;
    float d_ = acc[q].x * ad.x + acc[q].y * ad.y + acc[q].z * ad.z + acc[q].w * ad.w;
    #pragma unroll
    for (int off = 1; off < 16; off <<= 1) {
      s_ += __shfl_xor(s_, off, 64);
      d_ += __shfl_xor(d_, off, 64);
    }
    if (fg == 0) {
      int r = rg * 2 + q;
      src[h * N + i0 + r] = s_;
      dst[h * N + i0 + r] = d_;
    }
  }

  __syncthreads();
  #pragma unroll
  for (int q = 0; q < 2; ++q) {
    *(float4*)&xls[(rg * 2 + q) * 68 + fg * 4] = acc[q];
  }
  __syncthreads();

  {
    const int lane = t & 63;
    const int g    = t >> 6;
    const int q    = lane >> 4;
    const int m    = lane & 15;
    short8 bv;
    #pragma unroll
    for (int r = 0; r < 8; ++r) {
      bv[r] = (short)f2bf(xls[(q * 8 + r) * 68 + g * 16 + m]);
    }
    ((short8*)xtB)[((size_t)(h * 128 + bx) * 4 + g) * 64 + lane] = bv;
  }
}

// ---------------------------------------------------------------------------
// Kernel 2: fused flash PV + in-block j-reduction. grid (128, HEADS), block
// 512 = 8 waves. Each wave runs the 16-chunk inner loop on its own 512-j
// slice; 8 fp32 partial-O/l sets are reduced in LDS (2 rounds) and the FINAL
// normalized output is written directly. fp32 accumulate end-to-end.
// ---------------------------------------------------------------------------
__global__ __launch_bounds__(512) void k_flash(const unsigned* __restrict__ mb,
                                               const float* __restrict__ src,
                                               const float* __restrict__ dst,
                                               const short* __restrict__ xtB,
                                               float* __restrict__ out) {
  // 4 reduce slots x 32 rows x RSTR floats = 34.8 KB.
  // First 4096 floats double as the dst[h] cache during the j-loop.
  __shared__ __align__(16) float smem[4 * 32 * RSTR];
  const int t    = threadIdx.x;
  const int lane = t & 63;
  const int w    = t >> 6;            // wave id = j-slice id
  const int h    = blockIdx.y;
  const int i0   = blockIdx.x * 32;
  const int q    = lane >> 4;
  const int m    = lane & 15;
  const int koff = q * 8;
  const int jbase = w * JLEN;

  // stage full dst row for this head: 4096 floats
  {
    const float4* dg = (const float4*)(dst + (size_t)h * N);
    float4* ds4 = (float4*)smem;
    ds4[t]       = dg[t];
    ds4[t + 512] = dg[t + 512];
  }

  float sv = (lane < 32) ? src[h * N + i0 + lane] : 0.f;
  const float s0 = __shfl(sv, m, 64);
  const float s1 = __shfl(sv, 16 + m, 64);
  __syncthreads();

  f32x4 acc0[4], acc1[4], accL0, accL1;
  #pragma unroll
  for (int g = 0; g < 4; ++g) { acc0[g] = (f32x4)(0.f); acc1[g] = (f32x4)(0.f); }
  accL0 = (f32x4)(0.f);
  accL1 = (f32x4)(0.f);

  short8 ones;
  #pragma unroll
  for (int r = 0; r < 8; ++r) ones[r] = (short)0x3F80;

  const f32x2 s02 = (f32x2)(s0);
  const f32x2 s12 = (f32x2)(s1);

  const unsigned* mrow0 = mb + (size_t)(i0 + m) * 128 + w * NC;
  const unsigned* mrow1 = mb + (size_t)(i0 + 16 + m) * 128 + w * NC;
  const short8* xbb = (const short8*)xtB + ((size_t)(h * 128 + w * NC) * 4) * 64 + lane;

#define LOADC(DM0, DM1, DB, CIDX) do {                                     \
    DM0 = mrow0[CIDX];                                                     \
    DM1 = mrow1[CIDX];                                                     \
    const short8* bb_ = xbb + (size_t)(CIDX) * 256;                        \
    DB[0] = bb_[0]; DB[1] = bb_[64]; DB[2] = bb_[128]; DB[3] = bb_[192];   \
  } while (0)

#define COMPUTE(CM0, CM1, CB, C) do {                                      \
    const float* dp_ = &smem[jbase + (C) * 32 + koff];                     \
    union { float4 v[2]; f32x2 h2[4]; float f[8]; } du;                    \
    du.v[0] = *(const float4*)dp_;                                         \
    du.v[1] = *(const float4*)(dp_ + 4);                                   \
    unsigned ms0 = (CM0) >> koff;                                          \
    unsigned ms1 = (CM1) >> koff;                                          \
    int av0[4], av1[4];                                                    \
    _Pragma("unroll")                                                      \
    for (int r2 = 0; r2 < 4; ++r2) {                                       \
      f32x2 d2 = du.h2[r2];                                                \
      f32x2 e0 = s02 + d2;                                                 \
      f32x2 el0 = __builtin_elementwise_max(e0, e0 * NEG);                 \
      f32x2 e1 = s12 + d2;                                                 \
      f32x2 el1 = __builtin_elementwise_max(e1, e1 * NEG);                 \
      float p0a = exp2_fast(el0.x), p0b = exp2_fast(el0.y);                \
      float p1a = exp2_fast(el1.x), p1b = exp2_fast(el1.y);                \
      MSEL(p0a, ms0, 2 * r2);  MSEL(p0b, ms0, 2 * r2 + 1);                 \
      MSEL(p1a, ms1, 2 * r2);  MSEL(p1b, ms1, 2 * r2 + 1);                 \
      av0[r2] = pack_bf2(p0a, p0b);                                        \
      av1[r2] = pack_bf2(p1a, p1b);                                        \
    }                                                                      \
    short8 af0 = __builtin_bit_cast(short8, *(int4*)av0);                  \
    short8 af1 = __builtin_bit_cast(short8, *(int4*)av1);                  \
    acc0[0] = __builtin_amdgcn_mfma_f32_16x16x32_bf16(af0, CB[0], acc0[0], 0, 0, 0); \
    acc0[1] = __builtin_amdgcn_mfma_f32_16x16x32_bf16(af0, CB[1], acc0[1], 0, 0, 0); \
    acc0[2] = __builtin_amdgcn_mfma_f32_16x16x32_bf16(af0, CB[2], acc0[2], 0, 0, 0); \
    acc0[3] = __builtin_amdgcn_mfma_f32_16x16x32_bf16(af0, CB[3], acc0[3], 0, 0, 0); \
    accL0   = __builtin_amdgcn_mfma_f32_16x16x32_bf16(af0, ones,  accL0,   0, 0, 0); \
    acc1[0] = __builtin_amdgcn_mfma_f32_16x16x32_bf16(af1, CB[0], acc1[0], 0, 0, 0); \
    acc1[1] = __builtin_amdgcn_mfma_f32_16x16x32_bf16(af1, CB[1], acc1[1], 0, 0, 0); \
    acc1[2] = __builtin_amdgcn_mfma_f32_16x16x32_bf16(af1, CB[2], acc1[2], 0, 0, 0); \
    acc1[3] = __builtin_amdgcn_mfma_f32_16x16x32_bf16(af1, CB[3], acc1[3], 0, 0, 0); \
    accL1   = __builtin_amdgcn_mfma_f32_16x16x32_bf16(af1, ones,  accL1,   0, 0, 0); \
  } while (0)

  unsigned cM0, cM1, nM0, nM1;
  short8 cB[4], nB[4];
  LOADC(cM0, cM1, cB, 0);

  for (int c = 0; c < NC; ++c) {
    const int cn = (c + 1 < NC) ? c + 1 : c;
    LOADC(nM0, nM1, nB, cn);

    COMPUTE(cM0, cM1, cB, c);

    cM0 = nM0; cM1 = nM1;
    #pragma unroll
    for (int z = 0; z < 4; ++z) cB[z] = nB[z];
  }
#undef LOADC
#undef COMPUTE

  // ---- in-block reduction of 8 wave partials (fp32, 2 rounds) -----------
  // row layout per slot: [row 0..31][RSTR floats: 64 O-cols + l at col 64]
  // store/add addr = row*68 + col -> worst 2-way bank alias (free, m136).
#define RED_ST(SLOT) do {                                                  \
    float* part_ = smem + (SLOT) * (32 * RSTR);                            \
    _Pragma("unroll")                                                      \
    for (int g = 0; g < 4; ++g)                                            \
      _Pragma("unroll")                                                    \
      for (int rr = 0; rr < 4; ++rr) {                                     \
        part_[(q * 4 + rr) * RSTR + g * 16 + m]      = acc0[g][rr];        \
        part_[(q * 4 + rr + 16) * RSTR + g * 16 + m] = acc1[g][rr];        \
      }                                                                    \
    if (m == 0) {                                                          \
      _Pragma("unroll")                                                    \
      for (int rr = 0; rr < 4; ++rr) {                                     \
        part_[(q * 4 + rr) * RSTR + 64]      = accL0[rr];                  \
        part_[(q * 4 + rr + 16) * RSTR + 64] = accL1[rr];                  \
      }                                                                    \
    }                                                                      \
  } while (0)
#define RED_ADD(SLOT) do {                                                 \
    const float* part_ = smem + (SLOT) * (32 * RSTR);                      \
    _Pragma("unroll")                                                      \
    for (int g = 0; g < 4; ++g)                                            \
      _Pragma("unroll")                                                    \
      for (int rr = 0; rr < 4; ++rr) {                                     \
        acc0[g][rr] += part_[(q * 4 + rr) * RSTR + g * 16 + m];            \
        acc1[g][rr] += part_[(q * 4 + rr + 16) * RSTR + g * 16 + m];       \
      }                                                                    \
    _Pragma("unroll")                                                      \
    for (int rr = 0; rr < 4; ++rr) {                                       \
      accL0[rr] += part_[(q * 4 + rr) * RSTR + 64];                        \
      accL1[rr] += part_[(q * 4 + rr + 16) * RSTR + 64];                   \
    }                                                                      \
  } while (0)

  __syncthreads();                    // j-loop done; dst cache now dead
  if (w >= 4) RED_ST(w - 4);          // slots 0..3 <- waves 4..7
  __syncthreads();
  if (w < 4) { RED_ADD(w); RED_ST(w); }  // slots 0..3 <- pairwise sums
  __syncthreads();
#undef RED_ST
#undef RED_ADD

  // ---- final 4-slot sum + normalize + coalesced store -------------------
  {
    const int row = t >> 4;
    const int c4  = t & 15;
    const float* p = smem + row * RSTR + c4 * 4;
    const float* pl = smem + row * RSTR + 64;
    float4 v = *(const float4*)p;
    float l = pl[0];
    #pragma unroll
    for (int slot = 1; slot < 4; ++slot) {
      const float4 u = *(const float4*)(p + slot * (32 * RSTR));
      v.x += u.x; v.y += u.y; v.z += u.z; v.w += u.w;
      l += pl[slot * (32 * RSTR)];
    }
    const float il = 1.f / l;
    v.x *= il; v.y *= il; v.z *= il; v.w *= il;
    ((float4*)out)[(size_t)(i0 + row) * 64 + h * 16 + c4] = v;
  }
}

extern "C" void kernel_launch(void* const* d_in, const int* in_sizes, int n_in,
                              void* d_out, int out_size, void* d_ws, size_t ws_size,
                              hipStream_t stream) {
  const float* x   = (const float*)d_in[0];
  const float* W   = (const float*)d_in[1];
  const float* a   = (const float*)d_in[2];
  const int*   adj = (const int*)d_in[3];
  float* out = (float*)d_out;

  float* ws    = (float*)d_ws;
  short* xtB   = (short*)ws;                                // H*N*64 bf16 = 2 MB
  float* src   = ws + 524288;                               // H*N
  float* dst   = src + HEADS * N;                           // H*N
  unsigned* mb = (unsigned*)(dst + HEADS * N);              // N*128 u32 = 2 MB

  k_prep<<<dim3(512 + N * N / 8 / 256), 256, 0, stream>>>(x, W, a, adj, xtB, src, dst,
                                                          (unsigned char*)mb);
  k_flash<<<dim3(N / 32, HEADS), 512, 0, stream>>>(mb, src, dst, xtB, out);
}